// Round 1
// baseline (98.543 us; speedup 1.0000x reference)
//
#include <hip/hip_runtime.h>
#include <stdint.h>

typedef unsigned short u16;
typedef unsigned int u32;
typedef __attribute__((ext_vector_type(4))) float f32x4;
typedef __attribute__((ext_vector_type(4))) u16 u16x4;
typedef __attribute__((ext_vector_type(8))) __bf16 bf16x8;

__device__ __forceinline__ u16 f2bf(float f) {
  u32 u = __builtin_bit_cast(u32, f);
  u = (u + 0x7FFFu + ((u >> 16) & 1u)) >> 16;   // RNE
  return (u16)u;
}

__device__ __forceinline__ void gload_lds16(const void* g, void* l) {
  __builtin_amdgcn_global_load_lds(
      (const __attribute__((address_space(1))) void*)(uintptr_t)(g),
      (__attribute__((address_space(3))) void*)(u32)(uintptr_t)(l),
      16, 0, 0);
}

// ---------------- fp32 -> bf16, identity layout ----------------
__global__ void k_cvt(const float* __restrict__ in, u16* __restrict__ out, int n4) {
  int i = blockIdx.x * 256 + threadIdx.x;
  if (i >= n4) return;
  f32x4 v = ((const f32x4*)in)[i];
  u16x4 o = { f2bf(v.x), f2bf(v.y), f2bf(v.z), f2bf(v.w) };
  ((u16x4*)out)[i] = o;
}

// -------- transpose+convert: in [K][N] f32 -> out [N][K] bf16 ----------
__global__ void k_transpose(const float* __restrict__ in, u16* __restrict__ out,
                            int K, int N) {
  __shared__ float tile[32][33];
  int n0 = blockIdx.x * 32, k0 = blockIdx.y * 32;
  int t = threadIdx.x;
  int c = t & 31, r0 = t >> 5;
#pragma unroll
  for (int i = 0; i < 4; ++i)
    tile[r0 + i * 8][c] = in[(size_t)(k0 + r0 + i * 8) * N + n0 + c];
  __syncthreads();
  int on = t >> 3, ok = (t & 7) * 4;
  u16x4 o = { f2bf(tile[ok + 0][on]), f2bf(tile[ok + 1][on]),
              f2bf(tile[ok + 2][on]), f2bf(tile[ok + 3][on]) };
  *(u16x4*)&out[(size_t)(n0 + on) * K + k0 + ok] = o;
}

// ---------------- 128x128 tile MFMA GEMM (m97 structure) ----------------
// C[m][n] = sum_k A[m][k] * Bt[n][k] + bias[n]
// EPI=0: n<1024 -> outq bf16 [M][1024]; n>=1024 -> present f32 [B][2][16][2048][64]
// EPI=1: outp f32 [M][N]
template <int EPI>
__global__ __launch_bounds__(256) void k_gemm(
    const u16* __restrict__ A, const u16* __restrict__ Bt,
    const float* __restrict__ bias, u16* __restrict__ outq,
    float* __restrict__ outp, int M, int N, int K) {
  __shared__ u16 a_lds[128 * 64];
  __shared__ u16 b_lds[128 * 64];
  const int t = threadIdx.x;
  const int lane = t & 63, w = t >> 6;
  const int m0 = blockIdx.y * 128, n0 = blockIdx.x * 128;
  const int srow = t >> 3;                     // staging row (+i*32)
  const int scb = (t & 7) * 16;                // staging col byte
  const int ssw = scb ^ ((srow & 7) << 4);     // inverse-swizzled source col
  const size_t pitch = (size_t)K * 2;
  const char* aS = (const char*)A + (size_t)(m0 + srow) * pitch + ssw;
  const char* bS = (const char*)Bt + (size_t)(n0 + srow) * pitch + ssw;
  char* al = (char*)a_lds + t * 16;
  char* bl = (char*)b_lds + t * 16;
  const int wm = (w >> 1) * 64, wn = (w & 1) * 64;
  const int cc = lane & 15, g = lane >> 4;

  f32x4 acc[4][4] = {};

  for (int kt = 0; kt < K; kt += 64) {
    __syncthreads();
#pragma unroll
    for (int i = 0; i < 4; ++i) {
      gload_lds16(aS + (size_t)kt * 2 + (size_t)i * 32 * pitch, al + i * 4096);
      gload_lds16(bS + (size_t)kt * 2 + (size_t)i * 32 * pitch, bl + i * 4096);
    }
    __syncthreads();
#pragma unroll
    for (int kk = 0; kk < 2; ++kk) {
      bf16x8 af[4], bf_[4];
#pragma unroll
      for (int mf = 0; mf < 4; ++mf) {
        int row = wm + mf * 16 + cc;
        af[mf] = *(const bf16x8*)((const char*)a_lds + row * 128 +
                                  ((kk * 64 + g * 16) ^ ((row & 7) << 4)));
      }
#pragma unroll
      for (int nf = 0; nf < 4; ++nf) {
        int row = wn + nf * 16 + cc;
        bf_[nf] = *(const bf16x8*)((const char*)b_lds + row * 128 +
                                   ((kk * 64 + g * 16) ^ ((row & 7) << 4)));
      }
#pragma unroll
      for (int mf = 0; mf < 4; ++mf)
#pragma unroll
        for (int nf = 0; nf < 4; ++nf)
          acc[mf][nf] = __builtin_amdgcn_mfma_f32_16x16x32_bf16(
              af[mf], bf_[nf], acc[mf][nf], 0, 0, 0);
    }
  }

  float bv[4];
#pragma unroll
  for (int nf = 0; nf < 4; ++nf) bv[nf] = bias[n0 + wn + nf * 16 + cc];

#pragma unroll
  for (int mf = 0; mf < 4; ++mf)
#pragma unroll
    for (int nf = 0; nf < 4; ++nf) {
      int n = n0 + wn + nf * 16 + cc;
#pragma unroll
      for (int j = 0; j < 4; ++j) {
        int m = m0 + wm + mf * 16 + g * 4 + j;
        float v = acc[mf][nf][j] + bv[nf];
        if (EPI == 0) {
          if (n < 1024) {
            outq[(size_t)m * 1024 + n] = f2bf(v);
          } else {
            int nn = n - 1024;
            int kv = nn >> 10, n2 = nn & 1023;
            int bb = m >> 11, ss = m & 2047;
            outp[((((size_t)bb * 2 + kv) * 16 + (n2 >> 6)) * 2048 + ss) * 64 +
                 (n2 & 63)] = v;
          }
        } else {
          outp[(size_t)m * N + n] = v;
        }
      }
    }
}

// ---------------- fused sparse attention ----------------
// grid (qb=16, h=16, b=2), 256 threads. Per block: 128 q rows.
// gathered keys: r<128 -> local row qb*128+r ; r>=128 -> summary row
// ((r-128)/8)*128 + 120 + (r-128)%8  (masked unless its block < qb)
__global__ __launch_bounds__(256) void k_attn(const u16* __restrict__ qws,
                                              const float* __restrict__ present,
                                              u16* __restrict__ hws) {
  const int qb = blockIdx.x, h = blockIdx.y, b = blockIdx.z;
  const int t = threadIdx.x, lane = t & 63, w = t >> 6;
  const int cc = lane & 15, g = lane >> 4;

  __shared__ u16 k_lds[256 * 72];      // [key][72] pad->144B rows
  __shared__ u16 q_lds[128 * 72];      // [q][72]
  __shared__ u16 vt_lds[64 * 264];     // [d][264] pad->528B rows (V^T)
  __shared__ u16 p_lds[4][32 * 136];   // per-wave P [32 q][136] (128-key chunk)
  __shared__ float rsum[4][32];

  const float* kbase = present + ((size_t)(b * 2 + 0) * 16 + h) * (2048 * 64);
  const float* vbase = present + ((size_t)(b * 2 + 1) * 16 + h) * (2048 * 64);

  // ---- stage K (fp32->bf16) ----
  {
    int seg = t & 15;
#pragma unroll
    for (int iter = 0; iter < 16; ++iter) {
      int r = (t >> 4) + iter * 16;
      int idx = r - 128;
      int gr = (r < 128) ? (qb * 128 + r) : ((idx >> 3) * 128 + 120 + (idx & 7));
      f32x4 v = *(const f32x4*)(kbase + (size_t)gr * 64 + seg * 4);
      u16x4 o = { f2bf(v.x), f2bf(v.y), f2bf(v.z), f2bf(v.w) };
      *(u16x4*)&k_lds[r * 72 + seg * 4] = o;
    }
  }
  // ---- stage V -> V^T (in-register 4x4 transpose) ----
  {
    int seg = t & 15;
    int d0 = seg * 4;
#pragma unroll
    for (int iter = 0; iter < 4; ++iter) {
      int r0 = ((t >> 4) + iter * 16) * 4;
      f32x4 vv[4];
#pragma unroll
      for (int i = 0; i < 4; ++i) {
        int r = r0 + i;
        int idx = r - 128;
        int gr = (r < 128) ? (qb * 128 + r) : ((idx >> 3) * 128 + 120 + (idx & 7));
        vv[i] = *(const f32x4*)(vbase + (size_t)gr * 64 + d0);
      }
#pragma unroll
      for (int jd = 0; jd < 4; ++jd) {
        u16x4 o = { f2bf(vv[0][jd]), f2bf(vv[1][jd]),
                    f2bf(vv[2][jd]), f2bf(vv[3][jd]) };
        *(u16x4*)&vt_lds[(d0 + jd) * 264 + r0] = o;
      }
    }
  }
  // ---- stage Q (already bf16) ----
  {
    const char* qsrc = (const char*)qws +
        ((size_t)(b * 2048 + qb * 128 + (t >> 3)) * 1024 + (size_t)h * 64) * 2 +
        (t & 7) * 16;
#pragma unroll
    for (int iter = 0; iter < 4; ++iter) {
      int row = (t >> 3) + iter * 32;
      bf16x8 qv = *(const bf16x8*)(qsrc + (size_t)iter * 32 * 2048);
      *(bf16x8*)((char*)q_lds + row * 144 + (t & 7) * 16) = qv;
    }
  }
  __syncthreads();

  // ---- swapped QK^T: S^T = mfma(K, Q)  (rows=keys, cols=q) ----
  bf16x8 qf_[2][2];
#pragma unroll
  for (int qf = 0; qf < 2; ++qf)
#pragma unroll
    for (int kk = 0; kk < 2; ++kk)
      qf_[qf][kk] = *(const bf16x8*)((const char*)q_lds +
                                     (w * 32 + qf * 16 + cc) * 144 + kk * 64 + g * 16);

  f32x4 s[16][2] = {};
#pragma unroll
  for (int kf = 0; kf < 16; ++kf)
#pragma unroll
    for (int kk = 0; kk < 2; ++kk) {
      bf16x8 kfr = *(const bf16x8*)((const char*)k_lds +
                                    (kf * 16 + cc) * 144 + kk * 64 + g * 16);
#pragma unroll
      for (int qf = 0; qf < 2; ++qf)
        s[kf][qf] = __builtin_amdgcn_mfma_f32_16x16x32_bf16(kfr, qf_[qf][kk],
                                                            s[kf][qf], 0, 0, 0);
    }

  // ---- mask + softmax (per-lane 64 keys + 4-lane-group shfl reduce) ----
  const int nsum = 128 + 8 * qb;
#pragma unroll
  for (int qf = 0; qf < 2; ++qf) {
    int q_local = w * 32 + qf * 16 + cc;
    float mx = -1e30f;
#pragma unroll
    for (int kf = 0; kf < 16; ++kf)
#pragma unroll
      for (int j = 0; j < 4; ++j) {
        int key = kf * 16 + g * 4 + j;
        float v = s[kf][qf][j] * 0.125f;
        bool vis = (key < 128) ? (key <= q_local) : (key < nsum);
        v = vis ? v : -1e30f;
        s[kf][qf][j] = v;
        mx = fmaxf(mx, v);
      }
    mx = fmaxf(mx, __shfl_xor(mx, 16));
    mx = fmaxf(mx, __shfl_xor(mx, 32));
    float sum = 0.f;
#pragma unroll
    for (int kf = 0; kf < 16; ++kf)
#pragma unroll
      for (int j = 0; j < 4; ++j) {
        float p = exp2f((s[kf][qf][j] - mx) * 1.44269504088896f);
        s[kf][qf][j] = p;
        sum += p;
      }
    sum += __shfl_xor(sum, 16);
    sum += __shfl_xor(sum, 32);
    if (g == 0) rsum[w][qf * 16 + cc] = sum;
  }

  // ---- PV in 2 chunks of 128 keys (per-wave P buffer, no barrier needed) ----
  f32x4 o_[2][4] = {};
#pragma unroll
  for (int ch = 0; ch < 2; ++ch) {
#pragma unroll
    for (int qf = 0; qf < 2; ++qf)
#pragma unroll
      for (int kf2 = 0; kf2 < 8; ++kf2) {
        int kf = ch * 8 + kf2;
        u16x4 o = { f2bf(s[kf][qf][0]), f2bf(s[kf][qf][1]),
                    f2bf(s[kf][qf][2]), f2bf(s[kf][qf][3]) };
        *(u16x4*)&p_lds[w][(qf * 16 + cc) * 136 + kf2 * 16 + g * 4] = o;
      }
#pragma unroll
    for (int kk = 0; kk < 4; ++kk) {
      bf16x8 pa[2], vb[4];
#pragma unroll
      for (int mf = 0; mf < 2; ++mf)
        pa[mf] = *(const bf16x8*)((const char*)p_lds[w] +
                                  (mf * 16 + cc) * 272 + kk * 64 + g * 16);
#pragma unroll
      for (int nf = 0; nf < 4; ++nf)
        vb[nf] = *(const bf16x8*)((const char*)vt_lds +
                                  (nf * 16 + cc) * 528 + (ch * 4 + kk) * 64 + g * 16);
#pragma unroll
      for (int mf = 0; mf < 2; ++mf)
#pragma unroll
        for (int nf = 0; nf < 4; ++nf)
          o_[mf][nf] = __builtin_amdgcn_mfma_f32_16x16x32_bf16(pa[mf], vb[nf],
                                                               o_[mf][nf], 0, 0, 0);
    }
  }

  // ---- epilogue: divide by row sum, write merged-head bf16 ----
#pragma unroll
  for (int mf = 0; mf < 2; ++mf)
#pragma unroll
    for (int j = 0; j < 4; ++j) {
      float inv = 1.0f / rsum[w][mf * 16 + g * 4 + j];
      size_t row = (size_t)(b * 2048 + qb * 128 + w * 32 + mf * 16 + g * 4 + j);
#pragma unroll
      for (int nf = 0; nf < 4; ++nf)
        hws[row * 1024 + h * 64 + nf * 16 + cc] = f2bf(o_[mf][nf][j] * inv);
    }
}

extern "C" void kernel_launch(void* const* d_in, const int* in_sizes, int n_in,
                              void* d_out, int out_size, void* d_ws, size_t ws_size,
                              hipStream_t stream) {
  const float* x      = (const float*)d_in[0];  // [2,2048,1024]
  const float* w_attn = (const float*)d_in[1];  // [1024,3072]
  const float* b_attn = (const float*)d_in[2];  // [3072]
  const float* w_proj = (const float*)d_in[3];  // [1024,1024]
  const float* b_proj = (const float*)d_in[4];  // [1024]
  float* h_out   = (float*)d_out;               // 4,194,304 f32
  float* present = (float*)d_out + 4194304;     // [2][2][16][2048][64] f32

  char* ws = (char*)d_ws;
  u16* xbf = (u16*)(ws);                        // 8 MB  [4096][1024] bf16
  u16* qws = (u16*)(ws + (8u << 20));           // 8 MB  [4096][1024] bf16
  u16* wat = (u16*)(ws + (16u << 20));          // 6 MB  [3072][1024] bf16
  u16* wpt = (u16*)(ws + (22u << 20));          // 2 MB  [1024][1024] bf16
  u16* hws = xbf;                               // reuse (x dead after QKV GEMM)

  k_cvt<<<4096, 256, 0, stream>>>(x, xbf, 4096 * 1024 / 4);
  k_transpose<<<dim3(96, 32), 256, 0, stream>>>(w_attn, wat, 1024, 3072);
  k_transpose<<<dim3(32, 32), 256, 0, stream>>>(w_proj, wpt, 1024, 1024);
  k_gemm<0><<<dim3(24, 32), 256, 0, stream>>>(xbf, wat, b_attn, qws, present,
                                              4096, 3072, 1024);
  k_attn<<<dim3(16, 16, 2), 256, 0, stream>>>(qws, present, hws);
  k_gemm<1><<<dim3(8, 32), 256, 0, stream>>>(hws, wpt, b_proj, nullptr, h_out,
                                             4096, 1024, 1024);
}